// Round 4
// baseline (611.908 us; speedup 1.0000x reference)
//
#include <hip/hip_runtime.h>
#include <math.h>

#define N_PTS 50000
#define KNN_K 16

using bf16x8 = __attribute__((ext_vector_type(8))) __bf16;
using bf16x4 = __attribute__((ext_vector_type(4))) __bf16;
using f32x4  = __attribute__((ext_vector_type(4))) float;

// Branchless exact-GELU: erf via Abramowitz-Stegun 7.1.26 (|abs err| < 1.5e-7,
// far below bf16 ulp of h). rcp/exp are single HW instructions.
__device__ __forceinline__ float gelu_f(float x) {
    float u  = x * 0.7071067811865475f;
    float au = fabsf(u);
    float t  = __builtin_amdgcn_rcpf(1.0f + 0.3275911f * au);
    float p  = t*(0.254829592f + t*(-0.284496736f + t*(1.421413741f +
               t*(-1.453152027f + t*1.061405429f))));
    float e  = __expf(-u * u);
    float r  = 1.0f - p * e;          // erf(|u|)
    float er = copysignf(r, x);
    return 0.5f * x * (1.0f + er);
}

// ---------------------------------------------------------------------------
// Kernel 1: per-point features, interleaved: pg[n][0:64]=p0, pg[n][64:128]=p1
// ---------------------------------------------------------------------------
__global__ __launch_bounds__(256) void k1_pfeat(
    const float* __restrict__ xyz, const float* __restrict__ W1,
    const float* __restrict__ b1,  const float* __restrict__ W2,
    const float* __restrict__ b2,  float* __restrict__ pg)
{
    int i = blockIdx.x * 256 + threadIdx.x;
    if (i >= N_PTS) return;
    float x = xyz[3*i+0], y = xyz[3*i+1], z = xyz[3*i+2];
    float v[64];
    #pragma unroll
    for (int c = 0; c < 64; ++c)
        v[c] = b1[c] + x*W1[c] + y*W1[64+c] + z*W1[128+c];
    #pragma unroll 8
    for (int c = 0; c < 64; ++c) pg[(size_t)i*128 + c] = v[c];
    for (int c = 0; c < 64; ++c) {
        float a = b2[c];
        #pragma unroll
        for (int k = 0; k < 64; ++k) a += v[k] * W2[k*64 + c];
        pg[(size_t)i*128 + 64 + c] = a;
    }
}

// ---------------------------------------------------------------------------
// Kernel 3: repack W3a/W3b into bf16 MFMA fragments:
// wf[(t*4+s)*512 + lane*8 + j] = W[k=s*32+(lane>>4)*8+j][c=t*16+(lane&15)]
// wfA and wfB adjacent so k4 stages both with one linear 64 KB copy.
// ---------------------------------------------------------------------------
__global__ __launch_bounds__(256) void k3_wfrag(
    const float* __restrict__ W3a, const float* __restrict__ W3b,
    __bf16* __restrict__ wfA, __bf16* __restrict__ wfB)
{
    int ci = blockIdx.x * 256 + threadIdx.x;   // 0..2047 chunk id
    if (ci >= 2048) return;
    int t = ci >> 8, s = (ci >> 6) & 3, l = ci & 63;
    int k0 = s*32 + (l >> 4)*8;
    int c  = t*16 + (l & 15);
    #pragma unroll
    for (int j = 0; j < 8; ++j) {
        wfA[ci*8 + j] = (__bf16)W3a[(k0 + j)*128 + c];
        wfB[ci*8 + j] = (__bf16)W3b[(k0 + j)*128 + c];
    }
}

// ---------------------------------------------------------------------------
// Kernel 4: fused edge MLP, swapped-operand MFMA form.  One wave = one point.
// (a) neighbor-gather loads issued BEFORE the weight-staging ds_writes/barrier
// so their L2 latency hides under staging (counted vmcnt);
// (b) branchless A&S gelu replaces libm erff.
// LDS: 64 KB weights + 16 x 4352 B h-tiles = 130.5 KiB -> 1 block/CU,
// 4 waves/SIMD (VGPR capped at 128 by launch_bounds).
// ---------------------------------------------------------------------------
__global__ __launch_bounds__(1024, 4) void k4_mlp(
    const float* __restrict__ pg, const int* __restrict__ knn,
    const __bf16* __restrict__ wf,   // wfA (32 KB) followed by wfB (32 KB)
    const float* __restrict__ b3a, const float* __restrict__ b3b,
    float* __restrict__ out)
{
    __shared__ __align__(16) __bf16 lds_w[2*16384];     // 64 KB: wfA | wfB
    __shared__ __align__(16) __bf16 lds_h[16][16*136];  // 69.6 KB

    const int tid  = threadIdx.x;
    const int wave = tid >> 6;
    const int lane = tid & 63;
    const int lrow = lane & 15;   // edge slot kk (the MFMA n-dim)
    const int quad = lane >> 4;   // 0..3

    const int n = blockIdx.x * 16 + wave;         // exact: 3125*16 = 50000
    const int j = knn[n*KNN_K + lrow];            // this edge's neighbor

    // ---- issue weight-staging loads -----------------------------------------
    f32x4 wreg[4];
    {
        const f32x4* src = (const f32x4*)wf;
        #pragma unroll
        for (int u = 0; u < 4; ++u) wreg[u] = src[tid + u*1024];
    }

    // ---- issue gather loads (independent of LDS; fly during staging+barrier)
    const float* pj = pg + (size_t)j*128;
    const float* pn = pg + (size_t)n*128;
    float4 PJ[8], PN[8];
    #pragma unroll
    for (int s2 = 0; s2 < 4; ++s2) {
        // s2 0,1 -> p1 slices (cols 64..127); s2 2,3 -> p0 slices (cols 0..63)
        int o = ((s2 < 2) ? 64 + s2*32 : (s2 - 2)*32) + quad*8;
        PJ[2*s2]     = *(const float4*)(pj + o);
        PJ[2*s2 + 1] = *(const float4*)(pj + o + 4);
        PN[2*s2]     = *(const float4*)(pn + o);
        PN[2*s2 + 1] = *(const float4*)(pn + o + 4);
    }

    // ---- stage weights to LDS (waits only on wreg; gathers stay in flight) --
    {
        f32x4* dst = (f32x4*)lds_w;
        #pragma unroll
        for (int u = 0; u < 4; ++u) dst[tid + u*1024] = wreg[u];
    }
    __syncthreads();

    // ---- build feat fragments (B-operand layout) ----------------------------
    bf16x8 afrag[4];
    // cols 0..63 of feat: p1[j] - p1[n]
    #pragma unroll
    for (int s = 0; s < 2; ++s) {
        float4 a0 = PJ[2*s], a1 = PJ[2*s+1];
        float4 c0 = PN[2*s], c1 = PN[2*s+1];
        bf16x8 f;
        f[0] = (__bf16)(a0.x - c0.x); f[1] = (__bf16)(a0.y - c0.y);
        f[2] = (__bf16)(a0.z - c0.z); f[3] = (__bf16)(a0.w - c0.w);
        f[4] = (__bf16)(a1.x - c1.x); f[5] = (__bf16)(a1.y - c1.y);
        f[6] = (__bf16)(a1.z - c1.z); f[7] = (__bf16)(a1.w - c1.w);
        afrag[s] = f;
    }
    // cols 64..127: p_local = max_k p0[knn[k]] - p0[n] (butterfly over 16 lanes)
    #pragma unroll
    for (int s = 0; s < 2; ++s) {
        float4 g0 = PJ[4 + 2*s], g1 = PJ[5 + 2*s];
        float m[8] = {g0.x, g0.y, g0.z, g0.w, g1.x, g1.y, g1.z, g1.w};
        #pragma unroll
        for (int d = 1; d < 16; d <<= 1) {
            #pragma unroll
            for (int q = 0; q < 8; ++q)
                m[q] = fmaxf(m[q], __shfl_xor(m[q], d));
        }
        float4 c0 = PN[4 + 2*s], c1 = PN[5 + 2*s];
        bf16x8 f;
        f[0] = (__bf16)(m[0] - c0.x); f[1] = (__bf16)(m[1] - c0.y);
        f[2] = (__bf16)(m[2] - c0.z); f[3] = (__bf16)(m[3] - c0.w);
        f[4] = (__bf16)(m[4] - c1.x); f[5] = (__bf16)(m[5] - c1.y);
        f[6] = (__bf16)(m[6] - c1.z); f[7] = (__bf16)(m[7] - c1.w);
        afrag[2 + s] = f;
    }

    // ---- matmul1 (swapped): acc[t][i] = h[edge=lrow][outcol=t*16+quad*4+i] --
    f32x4 acc[8];
    #pragma unroll
    for (int t = 0; t < 8; ++t)
        acc[t] = *(const f32x4*)(b3a + t*16 + quad*4);
    #pragma unroll
    for (int s = 0; s < 4; ++s) {
        #pragma unroll
        for (int t = 0; t < 8; ++t) {
            bf16x8 w = *(const bf16x8*)(lds_w + (((t*4 + s)*64 + lane) << 3));
            acc[t] = __builtin_amdgcn_mfma_f32_16x16x32_bf16(w, afrag[s], acc[t], 0, 0, 0);
        }
    }

    // ---- branchless gelu, vectorized b64 LDS write --------------------------
    __bf16* hb = &lds_h[wave][0];
    #pragma unroll
    for (int t = 0; t < 8; ++t) {
        bf16x4 hv;
        #pragma unroll
        for (int i = 0; i < 4; ++i)
            hv[i] = (__bf16)gelu_f(acc[t][i]);
        *(bf16x4*)(hb + lrow*136 + t*16 + quad*4) = hv;
    }

    // ---- matmul2 (swapped): out[edge=lrow][outcol=t*16+quad*4+i] ------------
    f32x4 acc2[8];
    #pragma unroll
    for (int t = 0; t < 8; ++t)
        acc2[t] = *(const f32x4*)(b3b + t*16 + quad*4);
    #pragma unroll
    for (int s = 0; s < 4; ++s) {
        bf16x8 hfrag = *(const bf16x8*)(hb + lrow*136 + s*32 + quad*8);
        #pragma unroll
        for (int t = 0; t < 8; ++t) {
            bf16x8 w = *(const bf16x8*)(lds_w + 16384 + (((t*4 + s)*64 + lane) << 3));
            acc2[t] = __builtin_amdgcn_mfma_f32_16x16x32_bf16(w, hfrag, acc2[t], 0, 0, 0);
        }
    }

    // ---- store: float4 per (t), fully vectorized ----------------------------
    float* orow = out + (size_t)n * (KNN_K * 128) + (size_t)lrow * 128;
    #pragma unroll
    for (int t = 0; t < 8; ++t)
        *(f32x4*)(orow + t*16 + quad*4) = acc2[t];
}

// ---------------------------------------------------------------------------
extern "C" void kernel_launch(void* const* d_in, const int* in_sizes, int n_in,
                              void* d_out, int out_size, void* d_ws, size_t ws_size,
                              hipStream_t stream)
{
    const float* xyz = (const float*)d_in[0];
    const int*   knn = (const int*)  d_in[1];
    const float* W1  = (const float*)d_in[2];
    const float* b1  = (const float*)d_in[3];
    const float* W2  = (const float*)d_in[4];
    const float* b2  = (const float*)d_in[5];
    const float* W3a = (const float*)d_in[6];
    const float* b3a = (const float*)d_in[7];
    const float* W3b = (const float*)d_in[8];
    const float* b3b = (const float*)d_in[9];
    float* out = (float*)d_out;

    // workspace layout (~25.7 MB)
    float*  pg  = (float*)d_ws;                         // [N][128] = p0|p1
    __bf16* wfA = (__bf16*)(pg + (size_t)N_PTS * 128);  // 128*128 bf16
    __bf16* wfB = wfA + 128 * 128;                      // adjacent to wfA

    hipLaunchKernelGGL(k3_wfrag, dim3(8), dim3(256), 0, stream, W3a, W3b, wfA, wfB);
    hipLaunchKernelGGL(k1_pfeat, dim3((N_PTS + 255) / 256), dim3(256), 0, stream,
                       xyz, W1, b1, W2, b2, pg);
    hipLaunchKernelGGL(k4_mlp, dim3(N_PTS / 16), dim3(1024), 0, stream,
                       pg, knn, wfA, b3a, b3b, out);
}